// Round 14
// baseline (396.020 us; speedup 1.0000x reference)
//
#include <hip/hip_runtime.h>

// LightGCN on MI355X (gfx950).
// N = 150000 nodes, d = 64, nnz = 6.4M edges, 3 layers, 4096 queries.
// Pipeline: two-level radix scatter (super-bins 4096 rows -> fine bins 64 rows)
// -> per-bin LDS row sort -> wave-per-row gather SpMM on bf16 table using
// v_pk_fma_f32 dual-FMA (layers 1-2 full, layer 3 fused to query rows, f32 acc).

constexpr int D = 64;
constexpr int RB = 64;             // rows per fine bin
constexpr int BCAP = 3072;         // fine-bin capacity (lambda=2731, +6.5 sigma)
constexpr int SRB = 4096;          // rows per super-bin
constexpr int SCAP = 180224;       // super-bin capacity = 22*8192 (lambda~173K, +17 sigma)
constexpr int SCHUNK = 8192;       // A2 edges per workgroup
constexpr int CPS = SCAP / SCHUNK; // chunks per super-bin = 22
constexpr int CHUNK = 8192;        // A1 edges per workgroup (32/thread)
constexpr int SB_MAX = 64;         // super-bin LDS capacity (N <= 262144)

typedef float f32x2 __attribute__((ext_vector_type(2)));

__device__ __forceinline__ float bflo(unsigned u) { return __uint_as_float(u << 16); }
__device__ __forceinline__ float bfhi(unsigned u) { return __uint_as_float(u & 0xFFFF0000u); }
__device__ __forceinline__ float bf1(ushort u) { return __uint_as_float((unsigned)u << 16); }
__device__ __forceinline__ unsigned bfpack(float f0, float f1) {
    unsigned u0 = __float_as_uint(f0), u1 = __float_as_uint(f1);
    u0 = (u0 + 0x7FFFu + ((u0 >> 16) & 1u)) >> 16;   // round-to-nearest-even
    u1 = (u1 + 0x7FFFu + ((u1 >> 16) & 1u)) >> 16;
    return u0 | (u1 << 16);
}

// ---- pack e0 = [user_emb; item_emb] into bf16 table ----
__global__ __launch_bounds__(256) void pack_e0(const float4* __restrict__ u4,
                                               const float4* __restrict__ i4,
                                               uint2* __restrict__ ebf2,
                                               long long nU4, long long total4) {
    long long t = (long long)blockIdx.x * blockDim.x + threadIdx.x;
    if (t >= total4) return;
    float4 v = (t < nU4) ? u4[t] : i4[t - nU4];
    ebf2[t] = make_uint2(bfpack(v.x, v.y), bfpack(v.z, v.w));
}

// ---- init query accumulators with layer-0 embeddings (f32 inputs, exact) ----
__global__ __launch_bounds__(64) void gather_init(const float* __restrict__ ue,
                                                  const float* __restrict__ ie,
                                                  const int* __restrict__ uidx,
                                                  const int* __restrict__ iidx,
                                                  float* __restrict__ accU,
                                                  float* __restrict__ accI) {
    int j = blockIdx.x;
    int lane = threadIdx.x;
    accU[(size_t)j * D + lane] = ue[(size_t)uidx[j] * D + lane];
    accI[(size_t)j * D + lane] = ie[(size_t)iidx[j] * D + lane];
}

// ---- A1: scatter edges into super-bin regions (runs ~221 edges = 1.77KB) ----
// packed .x: bits[29:18] = row-in-super (12b), bits[17:0] = col ; .y = weight
__global__ __launch_bounds__(256) void scatter_super(const int2* __restrict__ idx2,
                                                     const float* __restrict__ adj,
                                                     int* __restrict__ scur,
                                                     int2* __restrict__ sbinned,
                                                     long long nnz, int nsup) {
    __shared__ int h[SB_MAX];
    __shared__ int rbase[SB_MAX];
    const int tid = threadIdx.x;
    if (tid < nsup) h[tid] = 0;
    __syncthreads();
    const long long base = (long long)blockIdx.x * CHUNK;
    const bool full = (base + CHUNK <= nnz);

    if (full) {
        #pragma unroll
        for (int bb = 0; bb < 2; ++bb) {
            long long g0 = base + bb * 4096 + (long long)tid * 16;
            int4 m[8];
            #pragma unroll
            for (int k = 0; k < 8; ++k) m[k] = *(const int4*)(idx2 + g0 + 2 * k);
            #pragma unroll
            for (int k = 0; k < 8; ++k) {
                atomicAdd(&h[m[k].x >> 12], 1);
                atomicAdd(&h[m[k].z >> 12], 1);
            }
        }
    } else {
        for (int i = tid; i < CHUNK; i += 256) {
            long long g = base + i;
            if (g < nnz) atomicAdd(&h[idx2[g].x >> 12], 1);
        }
    }
    __syncthreads();
    if (tid < nsup) {
        int v = h[tid];
        rbase[tid] = v ? atomicAdd(&scur[tid], v) : 0;
        h[tid] = 0;
    }
    __syncthreads();
    auto emit = [&](int row, int col, float w) {
        int s = row >> 12;
        int pos = rbase[s] + atomicAdd(&h[s], 1);
        if (pos < SCAP)   // statistically never taken; memory-safety clamp
            sbinned[(size_t)s * SCAP + pos] =
                make_int2(((row & (SRB - 1)) << 18) | col, __float_as_int(w));
    };
    if (full) {
        #pragma unroll
        for (int bb = 0; bb < 2; ++bb) {
            long long g0 = base + bb * 4096 + (long long)tid * 16;
            int4 m[8];
            float4 w[4];
            #pragma unroll
            for (int k = 0; k < 8; ++k) m[k] = *(const int4*)(idx2 + g0 + 2 * k);
            #pragma unroll
            for (int k = 0; k < 4; ++k) w[k] = *(const float4*)(adj + g0 + 4 * k);
            #pragma unroll
            for (int k = 0; k < 8; ++k) {
                emit(m[k].x, m[k].y, ((const float*)w)[2 * k]);
                emit(m[k].z, m[k].w, ((const float*)w)[2 * k + 1]);
            }
        }
    } else {
        for (int i = tid; i < CHUNK; i += 256) {
            long long g = base + i;
            if (g < nnz) {
                int2 rc = idx2[g];
                emit(rc.x, rc.y, adj[g]);
            }
        }
    }
}

// ---- A2: re-scatter each super-bin into its 64 fine bins (runs ~128 = 1KB) ----
// fine bin id (global) = s*64 + (row_in_super>>6) = row>>6.
// output .x: bits[23:18] = row-in-bin, bits[17:0] = col
__global__ __launch_bounds__(256) void scatter_fine(const int2* __restrict__ sbinned,
                                                    const int* __restrict__ scount,
                                                    int* __restrict__ cursor,
                                                    int2* __restrict__ binned) {
    __shared__ int h[64];
    __shared__ int rbase[64];
    const int tid = threadIdx.x;
    const int s = blockIdx.x / CPS;
    const int c = blockIdx.x % CPS;
    int len = scount[s];
    if (len > SCAP) len = SCAP;
    const int begin = c * SCHUNK;
    const int end = min(begin + SCHUNK, len);
    if (begin >= end) return;   // workgroup-uniform exit
    if (tid < 64) h[tid] = 0;
    __syncthreads();
    const int2* src = sbinned + (size_t)s * SCAP;
    const bool full = (end - begin == SCHUNK);

    if (full) {
        #pragma unroll
        for (int bb = 0; bb < 2; ++bb) {
            int g0 = begin + bb * 4096 + tid * 16;
            int4 m[8];
            #pragma unroll
            for (int k = 0; k < 8; ++k) m[k] = *(const int4*)(src + g0 + 2 * k);
            #pragma unroll
            for (int k = 0; k < 8; ++k) {
                atomicAdd(&h[(m[k].x >> 24) & 63], 1);
                atomicAdd(&h[(m[k].z >> 24) & 63], 1);
            }
        }
    } else {
        for (int i = begin + tid; i < end; i += 256)
            atomicAdd(&h[(src[i].x >> 24) & 63], 1);
    }
    __syncthreads();
    if (tid < 64) {
        int v = h[tid];
        rbase[tid] = v ? atomicAdd(&cursor[s * 64 + tid], v) : 0;
        h[tid] = 0;
    }
    __syncthreads();
    auto emit = [&](int x, int wbits) {
        int f = (x >> 24) & 63;
        int pos = rbase[f] + atomicAdd(&h[f], 1);
        if (pos < BCAP)   // statistically never taken; memory-safety clamp
            binned[(size_t)(s * 64 + f) * BCAP + pos] = make_int2(x & 0xFFFFFF, wbits);
    };
    if (full) {
        #pragma unroll
        for (int bb = 0; bb < 2; ++bb) {
            int g0 = begin + bb * 4096 + tid * 16;
            int4 m[8];
            #pragma unroll
            for (int k = 0; k < 8; ++k) m[k] = *(const int4*)(src + g0 + 2 * k);
            #pragma unroll
            for (int k = 0; k < 8; ++k) {
                emit(m[k].x, m[k].y);
                emit(m[k].z, m[k].w);
            }
        }
    } else {
        for (int i = begin + tid; i < end; i += 256) {
            int2 e = src[i];
            emit(e.x, e.y);
        }
    }
}

// ---- per-bin LDS sort: bin region -> row-sorted region + per-row (start,end) ----
__global__ __launch_bounds__(256) void bin_sort(int2* __restrict__ binned,
                                                const int* __restrict__ cursor,
                                                int2* __restrict__ row_se,
                                                int N) {
    __shared__ int2 buf[BCAP];    // 24 KB
    __shared__ int h[RB];
    __shared__ int lcur[RB];
    int b = blockIdx.x, tid = threadIdx.x;
    size_t bbase = (size_t)b * BCAP;
    int len = cursor[b];
    if (len > BCAP) len = BCAP;
    for (int i = tid; i < len; i += 256) buf[i] = binned[bbase + i];
    if (tid < RB) h[tid] = 0;
    __syncthreads();
    for (int i = tid; i < len; i += 256) atomicAdd(&h[(buf[i].x >> 18) & 63], 1);
    __syncthreads();
    if (tid < RB) {                          // wave 0: 64-wide exclusive scan
        int v = h[tid];
        int incl = v;
        #pragma unroll
        for (int off = 1; off < RB; off <<= 1) {
            int t = __shfl_up(incl, off, 64);
            if (tid >= off) incl += t;
        }
        int excl = incl - v;
        lcur[tid] = excl;
        int row = b * RB + tid;
        if (row < N) row_se[row] = make_int2((int)bbase + excl, (int)bbase + excl + v);
    }
    __syncthreads();
    for (int i = tid; i < len; i += 256) {
        int2 p = buf[i];
        int rb = (p.x >> 18) & 63;
        int pos = atomicAdd(&lcur[rb], 1);
        binned[bbase + pos] = make_int2(p.x & 0x3FFFF, p.y);   // strip rb
    }
}

// ---- SpMM (full): wave per row, 8 edges in flight, v_pk_fma_f32 dual-FMA ----
__global__ __launch_bounds__(256) void spmm_bf16(const int2* __restrict__ csr,
                                                 const int2* __restrict__ row_se,
                                                 const ushort* __restrict__ ebf,
                                                 ushort* __restrict__ ebf_next,
                                                 int N) {
    int tid = threadIdx.x;
    int row = blockIdx.x * 4 + (tid >> 6);
    if (row >= N) return;
    int lane = tid & 63, eg = lane >> 3, sub = lane & 7;
    int2 se = row_se[row];
    int s = se.x, len = se.y - se.x;
    f32x2 p0 = {0.f, 0.f}, p1 = {0.f, 0.f}, p2 = {0.f, 0.f}, p3 = {0.f, 0.f};
    #pragma unroll 2
    for (int i = eg; i < len; i += 8) {
        int2 cw = csr[s + i];
        float w = __int_as_float(cw.y);
        uint4 v = *(const uint4*)(ebf + (size_t)cw.x * D + sub * 8);   // 16B = 8 bf16
        f32x2 w2 = {w, w};
        f32x2 e0 = {bflo(v.x), bfhi(v.x)};
        f32x2 e1 = {bflo(v.y), bfhi(v.y)};
        f32x2 e2 = {bflo(v.z), bfhi(v.z)};
        f32x2 e3 = {bflo(v.w), bfhi(v.w)};
        asm("v_pk_fma_f32 %0, %1, %2, %0" : "+v"(p0) : "v"(e0), "v"(w2));
        asm("v_pk_fma_f32 %0, %1, %2, %0" : "+v"(p1) : "v"(e1), "v"(w2));
        asm("v_pk_fma_f32 %0, %1, %2, %0" : "+v"(p2) : "v"(e2), "v"(w2));
        asm("v_pk_fma_f32 %0, %1, %2, %0" : "+v"(p3) : "v"(e3), "v"(w2));
    }
    float a0 = p0.x, a1 = p0.y, a2 = p1.x, a3 = p1.y;
    float a4 = p2.x, a5 = p2.y, a6 = p3.x, a7 = p3.y;
    #pragma unroll
    for (int off = 8; off < 64; off <<= 1) {   // reduce across the 8 edge groups
        a0 += __shfl_xor(a0, off, 64); a1 += __shfl_xor(a1, off, 64);
        a2 += __shfl_xor(a2, off, 64); a3 += __shfl_xor(a3, off, 64);
        a4 += __shfl_xor(a4, off, 64); a5 += __shfl_xor(a5, off, 64);
        a6 += __shfl_xor(a6, off, 64); a7 += __shfl_xor(a7, off, 64);
    }
    if (eg == 0) {
        uint4 pk = make_uint4(bfpack(a0, a1), bfpack(a2, a3), bfpack(a4, a5), bfpack(a6, a7));
        *(uint4*)(ebf_next + (size_t)row * D + sub * 8) = pk;
    }
}

// ---- SpMM (layer 3, fused): query rows only, accumulate f32 into accU/accI ----
__global__ __launch_bounds__(256) void spmm_query(const int2* __restrict__ csr,
                                                  const int2* __restrict__ row_se,
                                                  const ushort* __restrict__ ebf,
                                                  const int* __restrict__ uidx,
                                                  const int* __restrict__ iidx,
                                                  float* __restrict__ accU,
                                                  float* __restrict__ accI,
                                                  int n_users, int nq) {
    int tid = threadIdx.x;
    int vq = blockIdx.x * 4 + (tid >> 6);
    if (vq >= 2 * nq) return;
    int lane = tid & 63, eg = lane >> 3, sub = lane & 7;
    bool isU = vq < nq;
    int j = isU ? vq : vq - nq;
    int row = isU ? uidx[j] : n_users + iidx[j];
    int2 se = row_se[row];
    int s = se.x, len = se.y - se.x;
    float a0 = 0, a1 = 0, a2 = 0, a3 = 0, a4 = 0, a5 = 0, a6 = 0, a7 = 0;
    #pragma unroll 2
    for (int i = eg; i < len; i += 8) {
        int2 cw = csr[s + i];
        float w = __int_as_float(cw.y);
        uint4 v = *(const uint4*)(ebf + (size_t)cw.x * D + sub * 8);
        a0 += w * bflo(v.x); a1 += w * bfhi(v.x);
        a2 += w * bflo(v.y); a3 += w * bfhi(v.y);
        a4 += w * bflo(v.z); a5 += w * bfhi(v.z);
        a6 += w * bflo(v.w); a7 += w * bfhi(v.w);
    }
    #pragma unroll
    for (int off = 8; off < 64; off <<= 1) {
        a0 += __shfl_xor(a0, off, 64); a1 += __shfl_xor(a1, off, 64);
        a2 += __shfl_xor(a2, off, 64); a3 += __shfl_xor(a3, off, 64);
        a4 += __shfl_xor(a4, off, 64); a5 += __shfl_xor(a5, off, 64);
        a6 += __shfl_xor(a6, off, 64); a7 += __shfl_xor(a7, off, 64);
    }
    if (eg == 0) {
        float* acc = (isU ? accU : accI) + (size_t)j * D + sub * 8;
        float4* f4 = (float4*)acc;
        float4 c0 = f4[0], c1 = f4[1];
        f4[0] = make_float4(c0.x + a0, c0.y + a1, c0.z + a2, c0.w + a3);
        f4[1] = make_float4(c1.x + a4, c1.y + a5, c1.z + a6, c1.w + a7);
    }
}

// ---- fold one layer's gathered rows (bf16 table) into the f32 accumulators ----
__global__ __launch_bounds__(64) void gather_acc(const ushort* __restrict__ e,
                                                 const int* __restrict__ uidx,
                                                 const int* __restrict__ iidx,
                                                 float* __restrict__ accU,
                                                 float* __restrict__ accI,
                                                 int n_users) {
    int j = blockIdx.x;
    int lane = threadIdx.x;
    accU[(size_t)j * D + lane] += bf1(e[(size_t)uidx[j] * D + lane]);
    accI[(size_t)j * D + lane] += bf1(e[((size_t)n_users + iidx[j]) * D + lane]);
}

// ---- final dot: out[j] = dot(accU[j]/4, accI[j]/4) ----
__global__ __launch_bounds__(64) void final_dot(const float* __restrict__ accU,
                                                const float* __restrict__ accI,
                                                float* __restrict__ out) {
    int j = blockIdx.x;
    int lane = threadIdx.x;
    float p = accU[(size_t)j * D + lane] * accI[(size_t)j * D + lane];
    #pragma unroll
    for (int off = 32; off > 0; off >>= 1) p += __shfl_down(p, off);
    if (lane == 0) out[j] = p * (1.0f / 16.0f);
}

extern "C" void kernel_launch(void* const* d_in, const int* in_sizes, int n_in,
                              void* d_out, int out_size, void* d_ws, size_t ws_size,
                              hipStream_t stream) {
    const float* user_emb = (const float*)d_in[0];
    const float* item_emb = (const float*)d_in[1];
    const float* adj_data = (const float*)d_in[2];
    const int* adj_indices = (const int*)d_in[3];
    const int* user_idx = (const int*)d_in[4];
    const int* item_idx = (const int*)d_in[5];
    float* out = (float*)d_out;

    const int n_users = in_sizes[0] / D;
    const int n_items = in_sizes[1] / D;
    const long long nnz = in_sizes[2];
    const int N = n_users + n_items;
    const int nq = in_sizes[4];
    const int NB = (N + RB - 1) / RB;            // 2344 fine bins
    const int nsup = (N + SRB - 1) / SRB;        // 37 super-bins
    const int NBF = nsup * 64;                   // fine-bin slots incl. padding

    // ---- workspace layout (~130 MB); sbinned ALIASES {ebf1,accU,accI,row_se},
    // all of which are first written only after scatter_fine has consumed it ----
    char* p = (char*)d_ws;
    auto alloc = [&](size_t bytes) { char* q = p; p += (bytes + 255) & ~(size_t)255; return q; };
    ushort* ebf0 = (ushort*)alloc((size_t)N * D * sizeof(ushort));     // 19.2 MB
    int2* binned = (int2*)alloc((size_t)NBF * BCAP * sizeof(int2));    // 58.2 MB
    // union region:
    char* uni = p;
    {
        size_t tail = 0;
        tail += ((size_t)N * D * sizeof(ushort) + 255) & ~(size_t)255;   // ebf1
        tail += 2 * (((size_t)nq * D * sizeof(float) + 255) & ~(size_t)255);
        tail += ((size_t)N * sizeof(int2) + 255) & ~(size_t)255;         // row_se
        size_t sb = ((size_t)nsup * SCAP * sizeof(int2) + 255) & ~(size_t)255;
        p += (sb > tail ? sb : tail);
    }
    int2* sbinned = (int2*)uni;                                        // 53.3 MB (dead after A2)
    char* q = uni;
    auto suballoc = [&](size_t bytes) { char* r = q; q += (bytes + 255) & ~(size_t)255; return r; };
    ushort* ebf1 = (ushort*)suballoc((size_t)N * D * sizeof(ushort));
    float* accU = (float*)suballoc((size_t)nq * D * sizeof(float));
    float* accI = (float*)suballoc((size_t)nq * D * sizeof(float));
    int2* row_se = (int2*)suballoc((size_t)N * sizeof(int2));
    int* cursor = (int*)alloc((size_t)NBF * sizeof(int));
    int* scur = (int*)alloc((size_t)SB_MAX * sizeof(int));

    const int2* idx2 = (const int2*)adj_indices;
    const int nChunksA1 = (int)((nnz + CHUNK - 1) / CHUNK);

    // ---- e0 (bf16) = concat(user_emb, item_emb) ----
    {
        long long total4 = (long long)N * (D / 4);
        long long nU4 = (long long)n_users * (D / 4);
        pack_e0<<<(int)((total4 + 255) / 256), 256, 0, stream>>>(
            (const float4*)user_emb, (const float4*)item_emb, (uint2*)ebf0, nU4, total4);
    }

    // ---- two-level radix scatter -> row-sorted fine bins ----
    (void)hipMemsetAsync(scur, 0, (size_t)SB_MAX * sizeof(int), stream);
    (void)hipMemsetAsync(cursor, 0, (size_t)NBF * sizeof(int), stream);
    scatter_super<<<nChunksA1, 256, 0, stream>>>(idx2, adj_data, scur, sbinned, nnz, nsup);
    scatter_fine<<<nsup * CPS, 256, 0, stream>>>(sbinned, scur, cursor, binned);
    bin_sort<<<NB, 256, 0, stream>>>(binned, cursor, row_se, N);

    // accU/accI alias sbinned -> init only after scatter_fine (stream-ordered)
    gather_init<<<nq, 64, 0, stream>>>(user_emb, item_emb, user_idx, item_idx, accU, accI);

    // ---- layers 1-2: full SpMM + query-row accumulation ----
    ushort* ebc = ebf0;
    ushort* ebn = ebf1;
    const int spmm_blocks = (N + 3) / 4;
    for (int layer = 0; layer < 2; ++layer) {
        spmm_bf16<<<spmm_blocks, 256, 0, stream>>>(binned, row_se, ebc, ebn, N);
        gather_acc<<<nq, 64, 0, stream>>>(ebn, user_idx, item_idx, accU, accI, n_users);
        ushort* t = ebc; ebc = ebn; ebn = t;
    }

    // ---- layer 3 fused: SpMM restricted to the 8192 query rows, f32 accumulate ----
    spmm_query<<<(2 * nq + 3) / 4, 256, 0, stream>>>(binned, row_se, ebc, user_idx, item_idx,
                                                     accU, accI, n_users, nq);

    final_dot<<<nq, 64, 0, stream>>>(accU, accI, out);
}

// Round 15
// 373.814 us; speedup vs baseline: 1.0594x; 1.0594x over previous
//
#include <hip/hip_runtime.h>

// LightGCN on MI355X (gfx950).
// N = 150000 nodes, d = 64, nnz = 6.4M edges, 3 layers, 4096 queries.
// Pipeline: two-level radix scatter (super-bins 4096 rows -> fine bins 64 rows)
// -> per-bin LDS row sort -> wave-per-row gather SpMM on bf16 table
// (layers 1-2 full, layer 3 fused to query rows, f32 accumulate).
// This is the empirically best configuration (round 10: 371.8 us).

constexpr int D = 64;
constexpr int RB = 64;             // rows per fine bin
constexpr int BCAP = 3072;         // fine-bin capacity (lambda=2731, +6.5 sigma)
constexpr int SRB = 4096;          // rows per super-bin
constexpr int SCAP = 180224;       // super-bin capacity = 22*8192 (lambda~173K, +17 sigma)
constexpr int SCHUNK = 8192;       // A2 edges per workgroup
constexpr int CPS = SCAP / SCHUNK; // chunks per super-bin = 22
constexpr int CHUNK = 8192;        // A1 edges per workgroup (32/thread)
constexpr int SB_MAX = 64;         // super-bin LDS capacity (N <= 262144)

__device__ __forceinline__ float bflo(unsigned u) { return __uint_as_float(u << 16); }
__device__ __forceinline__ float bfhi(unsigned u) { return __uint_as_float(u & 0xFFFF0000u); }
__device__ __forceinline__ float bf1(ushort u) { return __uint_as_float((unsigned)u << 16); }
__device__ __forceinline__ unsigned bfpack(float f0, float f1) {
    unsigned u0 = __float_as_uint(f0), u1 = __float_as_uint(f1);
    u0 = (u0 + 0x7FFFu + ((u0 >> 16) & 1u)) >> 16;   // round-to-nearest-even
    u1 = (u1 + 0x7FFFu + ((u1 >> 16) & 1u)) >> 16;
    return u0 | (u1 << 16);
}

// ---- pack e0 = [user_emb; item_emb] into bf16 table ----
__global__ __launch_bounds__(256) void pack_e0(const float4* __restrict__ u4,
                                               const float4* __restrict__ i4,
                                               uint2* __restrict__ ebf2,
                                               long long nU4, long long total4) {
    long long t = (long long)blockIdx.x * blockDim.x + threadIdx.x;
    if (t >= total4) return;
    float4 v = (t < nU4) ? u4[t] : i4[t - nU4];
    ebf2[t] = make_uint2(bfpack(v.x, v.y), bfpack(v.z, v.w));
}

// ---- init query accumulators with layer-0 embeddings (f32 inputs, exact) ----
__global__ __launch_bounds__(64) void gather_init(const float* __restrict__ ue,
                                                  const float* __restrict__ ie,
                                                  const int* __restrict__ uidx,
                                                  const int* __restrict__ iidx,
                                                  float* __restrict__ accU,
                                                  float* __restrict__ accI) {
    int j = blockIdx.x;
    int lane = threadIdx.x;
    accU[(size_t)j * D + lane] = ue[(size_t)uidx[j] * D + lane];
    accI[(size_t)j * D + lane] = ie[(size_t)iidx[j] * D + lane];
}

// ---- A1: scatter edges into super-bin regions (runs ~221 edges = 1.77KB) ----
// packed .x: bits[29:18] = row-in-super (12b), bits[17:0] = col ; .y = weight
__global__ __launch_bounds__(256) void scatter_super(const int2* __restrict__ idx2,
                                                     const float* __restrict__ adj,
                                                     int* __restrict__ scur,
                                                     int2* __restrict__ sbinned,
                                                     long long nnz, int nsup) {
    __shared__ int h[SB_MAX];
    __shared__ int rbase[SB_MAX];
    const int tid = threadIdx.x;
    if (tid < nsup) h[tid] = 0;
    __syncthreads();
    const long long base = (long long)blockIdx.x * CHUNK;
    const bool full = (base + CHUNK <= nnz);

    if (full) {
        #pragma unroll
        for (int bb = 0; bb < 2; ++bb) {
            long long g0 = base + bb * 4096 + (long long)tid * 16;
            int4 m[8];
            #pragma unroll
            for (int k = 0; k < 8; ++k) m[k] = *(const int4*)(idx2 + g0 + 2 * k);
            #pragma unroll
            for (int k = 0; k < 8; ++k) {
                atomicAdd(&h[m[k].x >> 12], 1);
                atomicAdd(&h[m[k].z >> 12], 1);
            }
        }
    } else {
        for (int i = tid; i < CHUNK; i += 256) {
            long long g = base + i;
            if (g < nnz) atomicAdd(&h[idx2[g].x >> 12], 1);
        }
    }
    __syncthreads();
    if (tid < nsup) {
        int v = h[tid];
        rbase[tid] = v ? atomicAdd(&scur[tid], v) : 0;
        h[tid] = 0;
    }
    __syncthreads();
    auto emit = [&](int row, int col, float w) {
        int s = row >> 12;
        int pos = rbase[s] + atomicAdd(&h[s], 1);
        if (pos < SCAP)   // statistically never taken; memory-safety clamp
            sbinned[(size_t)s * SCAP + pos] =
                make_int2(((row & (SRB - 1)) << 18) | col, __float_as_int(w));
    };
    if (full) {
        #pragma unroll
        for (int bb = 0; bb < 2; ++bb) {
            long long g0 = base + bb * 4096 + (long long)tid * 16;
            int4 m[8];
            float4 w[4];
            #pragma unroll
            for (int k = 0; k < 8; ++k) m[k] = *(const int4*)(idx2 + g0 + 2 * k);
            #pragma unroll
            for (int k = 0; k < 4; ++k) w[k] = *(const float4*)(adj + g0 + 4 * k);
            #pragma unroll
            for (int k = 0; k < 8; ++k) {
                emit(m[k].x, m[k].y, ((const float*)w)[2 * k]);
                emit(m[k].z, m[k].w, ((const float*)w)[2 * k + 1]);
            }
        }
    } else {
        for (int i = tid; i < CHUNK; i += 256) {
            long long g = base + i;
            if (g < nnz) {
                int2 rc = idx2[g];
                emit(rc.x, rc.y, adj[g]);
            }
        }
    }
}

// ---- A2: re-scatter each super-bin into its 64 fine bins (runs ~128 = 1KB) ----
// fine bin id (global) = s*64 + (row_in_super>>6) = row>>6.
// output .x: bits[23:18] = row-in-bin, bits[17:0] = col
__global__ __launch_bounds__(256) void scatter_fine(const int2* __restrict__ sbinned,
                                                    const int* __restrict__ scount,
                                                    int* __restrict__ cursor,
                                                    int2* __restrict__ binned) {
    __shared__ int h[64];
    __shared__ int rbase[64];
    const int tid = threadIdx.x;
    const int s = blockIdx.x / CPS;
    const int c = blockIdx.x % CPS;
    int len = scount[s];
    if (len > SCAP) len = SCAP;
    const int begin = c * SCHUNK;
    const int end = min(begin + SCHUNK, len);
    if (begin >= end) return;   // workgroup-uniform exit
    if (tid < 64) h[tid] = 0;
    __syncthreads();
    const int2* src = sbinned + (size_t)s * SCAP;
    const bool full = (end - begin == SCHUNK);

    if (full) {
        #pragma unroll
        for (int bb = 0; bb < 2; ++bb) {
            int g0 = begin + bb * 4096 + tid * 16;
            int4 m[8];
            #pragma unroll
            for (int k = 0; k < 8; ++k) m[k] = *(const int4*)(src + g0 + 2 * k);
            #pragma unroll
            for (int k = 0; k < 8; ++k) {
                atomicAdd(&h[(m[k].x >> 24) & 63], 1);
                atomicAdd(&h[(m[k].z >> 24) & 63], 1);
            }
        }
    } else {
        for (int i = begin + tid; i < end; i += 256)
            atomicAdd(&h[(src[i].x >> 24) & 63], 1);
    }
    __syncthreads();
    if (tid < 64) {
        int v = h[tid];
        rbase[tid] = v ? atomicAdd(&cursor[s * 64 + tid], v) : 0;
        h[tid] = 0;
    }
    __syncthreads();
    auto emit = [&](int x, int wbits) {
        int f = (x >> 24) & 63;
        int pos = rbase[f] + atomicAdd(&h[f], 1);
        if (pos < BCAP)   // statistically never taken; memory-safety clamp
            binned[(size_t)(s * 64 + f) * BCAP + pos] = make_int2(x & 0xFFFFFF, wbits);
    };
    if (full) {
        #pragma unroll
        for (int bb = 0; bb < 2; ++bb) {
            int g0 = begin + bb * 4096 + tid * 16;
            int4 m[8];
            #pragma unroll
            for (int k = 0; k < 8; ++k) m[k] = *(const int4*)(src + g0 + 2 * k);
            #pragma unroll
            for (int k = 0; k < 8; ++k) {
                emit(m[k].x, m[k].y);
                emit(m[k].z, m[k].w);
            }
        }
    } else {
        for (int i = begin + tid; i < end; i += 256) {
            int2 e = src[i];
            emit(e.x, e.y);
        }
    }
}

// ---- per-bin LDS sort: bin region -> row-sorted region + per-row (start,end) ----
__global__ __launch_bounds__(256) void bin_sort(int2* __restrict__ binned,
                                                const int* __restrict__ cursor,
                                                int2* __restrict__ row_se,
                                                int N) {
    __shared__ int2 buf[BCAP];    // 24 KB
    __shared__ int h[RB];
    __shared__ int lcur[RB];
    int b = blockIdx.x, tid = threadIdx.x;
    size_t bbase = (size_t)b * BCAP;
    int len = cursor[b];
    if (len > BCAP) len = BCAP;
    for (int i = tid; i < len; i += 256) buf[i] = binned[bbase + i];
    if (tid < RB) h[tid] = 0;
    __syncthreads();
    for (int i = tid; i < len; i += 256) atomicAdd(&h[(buf[i].x >> 18) & 63], 1);
    __syncthreads();
    if (tid < RB) {                          // wave 0: 64-wide exclusive scan
        int v = h[tid];
        int incl = v;
        #pragma unroll
        for (int off = 1; off < RB; off <<= 1) {
            int t = __shfl_up(incl, off, 64);
            if (tid >= off) incl += t;
        }
        int excl = incl - v;
        lcur[tid] = excl;
        int row = b * RB + tid;
        if (row < N) row_se[row] = make_int2((int)bbase + excl, (int)bbase + excl + v);
    }
    __syncthreads();
    for (int i = tid; i < len; i += 256) {
        int2 p = buf[i];
        int rb = (p.x >> 18) & 63;
        int pos = atomicAdd(&lcur[rb], 1);
        binned[bbase + pos] = make_int2(p.x & 0x3FFFF, p.y);   // strip rb
    }
}

// ---- SpMM (full): wave per row, 8 edges in flight, bf16 gathers, f32 acc ----
__global__ __launch_bounds__(256) void spmm_bf16(const int2* __restrict__ csr,
                                                 const int2* __restrict__ row_se,
                                                 const ushort* __restrict__ ebf,
                                                 ushort* __restrict__ ebf_next,
                                                 int N) {
    int tid = threadIdx.x;
    int row = blockIdx.x * 4 + (tid >> 6);
    if (row >= N) return;
    int lane = tid & 63, eg = lane >> 3, sub = lane & 7;
    int2 se = row_se[row];
    int s = se.x, len = se.y - se.x;
    float a0 = 0, a1 = 0, a2 = 0, a3 = 0, a4 = 0, a5 = 0, a6 = 0, a7 = 0;
    #pragma unroll 2
    for (int i = eg; i < len; i += 8) {
        int2 cw = csr[s + i];
        float w = __int_as_float(cw.y);
        uint4 v = *(const uint4*)(ebf + (size_t)cw.x * D + sub * 8);   // 16B = 8 bf16
        a0 += w * bflo(v.x); a1 += w * bfhi(v.x);
        a2 += w * bflo(v.y); a3 += w * bfhi(v.y);
        a4 += w * bflo(v.z); a5 += w * bfhi(v.z);
        a6 += w * bflo(v.w); a7 += w * bfhi(v.w);
    }
    #pragma unroll
    for (int off = 8; off < 64; off <<= 1) {
        a0 += __shfl_xor(a0, off, 64); a1 += __shfl_xor(a1, off, 64);
        a2 += __shfl_xor(a2, off, 64); a3 += __shfl_xor(a3, off, 64);
        a4 += __shfl_xor(a4, off, 64); a5 += __shfl_xor(a5, off, 64);
        a6 += __shfl_xor(a6, off, 64); a7 += __shfl_xor(a7, off, 64);
    }
    if (eg == 0) {
        uint4 pk = make_uint4(bfpack(a0, a1), bfpack(a2, a3), bfpack(a4, a5), bfpack(a6, a7));
        *(uint4*)(ebf_next + (size_t)row * D + sub * 8) = pk;
    }
}

// ---- SpMM (layer 3, fused): query rows only, accumulate f32 into accU/accI ----
__global__ __launch_bounds__(256) void spmm_query(const int2* __restrict__ csr,
                                                  const int2* __restrict__ row_se,
                                                  const ushort* __restrict__ ebf,
                                                  const int* __restrict__ uidx,
                                                  const int* __restrict__ iidx,
                                                  float* __restrict__ accU,
                                                  float* __restrict__ accI,
                                                  int n_users, int nq) {
    int tid = threadIdx.x;
    int vq = blockIdx.x * 4 + (tid >> 6);
    if (vq >= 2 * nq) return;
    int lane = tid & 63, eg = lane >> 3, sub = lane & 7;
    bool isU = vq < nq;
    int j = isU ? vq : vq - nq;
    int row = isU ? uidx[j] : n_users + iidx[j];
    int2 se = row_se[row];
    int s = se.x, len = se.y - se.x;
    float a0 = 0, a1 = 0, a2 = 0, a3 = 0, a4 = 0, a5 = 0, a6 = 0, a7 = 0;
    #pragma unroll 2
    for (int i = eg; i < len; i += 8) {
        int2 cw = csr[s + i];
        float w = __int_as_float(cw.y);
        uint4 v = *(const uint4*)(ebf + (size_t)cw.x * D + sub * 8);
        a0 += w * bflo(v.x); a1 += w * bfhi(v.x);
        a2 += w * bflo(v.y); a3 += w * bfhi(v.y);
        a4 += w * bflo(v.z); a5 += w * bfhi(v.z);
        a6 += w * bflo(v.w); a7 += w * bfhi(v.w);
    }
    #pragma unroll
    for (int off = 8; off < 64; off <<= 1) {
        a0 += __shfl_xor(a0, off, 64); a1 += __shfl_xor(a1, off, 64);
        a2 += __shfl_xor(a2, off, 64); a3 += __shfl_xor(a3, off, 64);
        a4 += __shfl_xor(a4, off, 64); a5 += __shfl_xor(a5, off, 64);
        a6 += __shfl_xor(a6, off, 64); a7 += __shfl_xor(a7, off, 64);
    }
    if (eg == 0) {
        float* acc = (isU ? accU : accI) + (size_t)j * D + sub * 8;
        float4* f4 = (float4*)acc;
        float4 c0 = f4[0], c1 = f4[1];
        f4[0] = make_float4(c0.x + a0, c0.y + a1, c0.z + a2, c0.w + a3);
        f4[1] = make_float4(c1.x + a4, c1.y + a5, c1.z + a6, c1.w + a7);
    }
}

// ---- fold one layer's gathered rows (bf16 table) into the f32 accumulators ----
__global__ __launch_bounds__(64) void gather_acc(const ushort* __restrict__ e,
                                                 const int* __restrict__ uidx,
                                                 const int* __restrict__ iidx,
                                                 float* __restrict__ accU,
                                                 float* __restrict__ accI,
                                                 int n_users) {
    int j = blockIdx.x;
    int lane = threadIdx.x;
    accU[(size_t)j * D + lane] += bf1(e[(size_t)uidx[j] * D + lane]);
    accI[(size_t)j * D + lane] += bf1(e[((size_t)n_users + iidx[j]) * D + lane]);
}

// ---- final dot: out[j] = dot(accU[j]/4, accI[j]/4) ----
__global__ __launch_bounds__(64) void final_dot(const float* __restrict__ accU,
                                                const float* __restrict__ accI,
                                                float* __restrict__ out) {
    int j = blockIdx.x;
    int lane = threadIdx.x;
    float p = accU[(size_t)j * D + lane] * accI[(size_t)j * D + lane];
    #pragma unroll
    for (int off = 32; off > 0; off >>= 1) p += __shfl_down(p, off);
    if (lane == 0) out[j] = p * (1.0f / 16.0f);
}

extern "C" void kernel_launch(void* const* d_in, const int* in_sizes, int n_in,
                              void* d_out, int out_size, void* d_ws, size_t ws_size,
                              hipStream_t stream) {
    const float* user_emb = (const float*)d_in[0];
    const float* item_emb = (const float*)d_in[1];
    const float* adj_data = (const float*)d_in[2];
    const int* adj_indices = (const int*)d_in[3];
    const int* user_idx = (const int*)d_in[4];
    const int* item_idx = (const int*)d_in[5];
    float* out = (float*)d_out;

    const int n_users = in_sizes[0] / D;
    const int n_items = in_sizes[1] / D;
    const long long nnz = in_sizes[2];
    const int N = n_users + n_items;
    const int nq = in_sizes[4];
    const int NB = (N + RB - 1) / RB;            // 2344 fine bins
    const int nsup = (N + SRB - 1) / SRB;        // 37 super-bins
    const int NBF = nsup * 64;                   // fine-bin slots incl. padding

    // ---- workspace layout (~130 MB); sbinned ALIASES {ebf1,accU,accI,row_se},
    // all of which are first written only after scatter_fine has consumed it ----
    char* p = (char*)d_ws;
    auto alloc = [&](size_t bytes) { char* q = p; p += (bytes + 255) & ~(size_t)255; return q; };
    ushort* ebf0 = (ushort*)alloc((size_t)N * D * sizeof(ushort));     // 19.2 MB
    int2* binned = (int2*)alloc((size_t)NBF * BCAP * sizeof(int2));    // 58.2 MB
    // union region:
    char* uni = p;
    {
        size_t tail = 0;
        tail += ((size_t)N * D * sizeof(ushort) + 255) & ~(size_t)255;   // ebf1
        tail += 2 * (((size_t)nq * D * sizeof(float) + 255) & ~(size_t)255);
        tail += ((size_t)N * sizeof(int2) + 255) & ~(size_t)255;         // row_se
        size_t sb = ((size_t)nsup * SCAP * sizeof(int2) + 255) & ~(size_t)255;
        p += (sb > tail ? sb : tail);
    }
    int2* sbinned = (int2*)uni;                                        // 53.3 MB (dead after A2)
    char* q = uni;
    auto suballoc = [&](size_t bytes) { char* r = q; q += (bytes + 255) & ~(size_t)255; return r; };
    ushort* ebf1 = (ushort*)suballoc((size_t)N * D * sizeof(ushort));
    float* accU = (float*)suballoc((size_t)nq * D * sizeof(float));
    float* accI = (float*)suballoc((size_t)nq * D * sizeof(float));
    int2* row_se = (int2*)suballoc((size_t)N * sizeof(int2));
    int* cursor = (int*)alloc((size_t)NBF * sizeof(int));
    int* scur = (int*)alloc((size_t)SB_MAX * sizeof(int));

    const int2* idx2 = (const int2*)adj_indices;
    const int nChunksA1 = (int)((nnz + CHUNK - 1) / CHUNK);

    // ---- e0 (bf16) = concat(user_emb, item_emb) ----
    {
        long long total4 = (long long)N * (D / 4);
        long long nU4 = (long long)n_users * (D / 4);
        pack_e0<<<(int)((total4 + 255) / 256), 256, 0, stream>>>(
            (const float4*)user_emb, (const float4*)item_emb, (uint2*)ebf0, nU4, total4);
    }

    // ---- two-level radix scatter -> row-sorted fine bins ----
    (void)hipMemsetAsync(scur, 0, (size_t)SB_MAX * sizeof(int), stream);
    (void)hipMemsetAsync(cursor, 0, (size_t)NBF * sizeof(int), stream);
    scatter_super<<<nChunksA1, 256, 0, stream>>>(idx2, adj_data, scur, sbinned, nnz, nsup);
    scatter_fine<<<nsup * CPS, 256, 0, stream>>>(sbinned, scur, cursor, binned);
    bin_sort<<<NB, 256, 0, stream>>>(binned, cursor, row_se, N);

    // accU/accI alias sbinned -> init only after scatter_fine (stream-ordered)
    gather_init<<<nq, 64, 0, stream>>>(user_emb, item_emb, user_idx, item_idx, accU, accI);

    // ---- layers 1-2: full SpMM + query-row accumulation ----
    ushort* ebc = ebf0;
    ushort* ebn = ebf1;
    const int spmm_blocks = (N + 3) / 4;
    for (int layer = 0; layer < 2; ++layer) {
        spmm_bf16<<<spmm_blocks, 256, 0, stream>>>(binned, row_se, ebc, ebn, N);
        gather_acc<<<nq, 64, 0, stream>>>(ebn, user_idx, item_idx, accU, accI, n_users);
        ushort* t = ebc; ebc = ebn; ebn = t;
    }

    // ---- layer 3 fused: SpMM restricted to the 8192 query rows, f32 accumulate ----
    spmm_query<<<(2 * nq + 3) / 4, 256, 0, stream>>>(binned, row_se, ebc, user_idx, item_idx,
                                                     accU, accI, n_users, nq);

    final_dot<<<nq, 64, 0, stream>>>(accU, accI, out);
}